// Round 1
// baseline (1085.547 us; speedup 1.0000x reference)
//
#include <hip/hip_runtime.h>
#include <hip/hip_bf16.h>
#include <cstdint>
#include <cstddef>

#define BB 64
#define NN 512
#define MM 512
#define DD 128

static constexpr float SINK_EPS_F = 0.05f;
static constexpr int   ITERS      = 80;
static constexpr float A_CONST    = 1.0f / 512.0f;   // 1/N
static constexpr float B_CONST    = 1.0f / 512.0f;   // 1/M

__device__ __forceinline__ float bflo(unsigned u) { return __uint_as_float(u << 16); }
__device__ __forceinline__ float bfhi(unsigned u) { return __uint_as_float(u & 0xffff0000u); }

// ---------------- kernel 1: row inverse norms ----------------
__global__ __launch_bounds__(256) void norm_kernel(const float* __restrict__ src,
                                                   const float* __restrict__ tgt,
                                                   float* __restrict__ inv_ns,
                                                   float* __restrict__ inv_nt) {
    int wave = (blockIdx.x * blockDim.x + threadIdx.x) >> 6;
    int lane = threadIdx.x & 63;
    const float* row;
    float* out;
    if (wave < BB * NN) { row = src + (size_t)wave * DD; out = inv_ns + wave; }
    else                { row = tgt + (size_t)(wave - BB * NN) * DD; out = inv_nt + (wave - BB * NN); }
    float2 v = ((const float2*)row)[lane];
    float s = v.x * v.x + v.y * v.y;
    #pragma unroll
    for (int off = 32; off; off >>= 1) s += __shfl_xor(s, off, 64);
    if (lane == 0) *out = 1.0f / fmaxf(sqrtf(s), 1e-12f);
}

// ---------------- kernel 2: normalized GEMM -> cost -> W=exp(-C/eps) (bf16) ----------------
#define TS  128
#define BK  32
#define PAD 36   // floats per LDS row (32 + pad), 144B row stride (16B aligned, 2-way banks)

__global__ __launch_bounds__(256) void cost_kernel(const float* __restrict__ S,
                                                   const float* __restrict__ T,
                                                   const float* __restrict__ inv_ns,
                                                   const float* __restrict__ inv_nt,
                                                   unsigned short* __restrict__ W) {
    __shared__ float sA[TS * PAD];
    __shared__ float sB[TS * PAD];
    int bid = blockIdx.x;
    int b  = bid >> 4;
    int i0 = ((bid >> 2) & 3) * TS;
    int j0 = (bid & 3) * TS;
    int t  = threadIdx.x;
    int tx = t & 15, ty = t >> 4;

    float acc[8][8] = {};

    for (int kc = 0; kc < DD; kc += BK) {
        // stage A and B tiles (scaled by inverse norms)
        #pragma unroll
        for (int p = 0; p < 4; ++p) {
            int row = (t >> 3) + p * 32;
            int c4  = t & 7;
            {
                int gr = b * NN + i0 + row;
                float4 v = ((const float4*)(S + (size_t)gr * DD + kc))[c4];
                float sc = inv_ns[gr];
                v.x *= sc; v.y *= sc; v.z *= sc; v.w *= sc;
                *(float4*)&sA[row * PAD + c4 * 4] = v;
            }
            {
                int gr = b * MM + j0 + row;
                float4 v = ((const float4*)(T + (size_t)gr * DD + kc))[c4];
                float sc = inv_nt[gr];
                v.x *= sc; v.y *= sc; v.z *= sc; v.w *= sc;
                *(float4*)&sB[row * PAD + c4 * 4] = v;
            }
        }
        __syncthreads();

        #pragma unroll 2
        for (int k4 = 0; k4 < BK; k4 += 4) {
            float4 av[8], bv[8];
            #pragma unroll
            for (int r = 0; r < 8; ++r) av[r] = *(const float4*)&sA[(ty + 16 * r) * PAD + k4];
            #pragma unroll
            for (int c = 0; c < 8; ++c) bv[c] = *(const float4*)&sB[(tx + 16 * c) * PAD + k4];
            #pragma unroll
            for (int r = 0; r < 8; ++r)
                #pragma unroll
                for (int c = 0; c < 8; ++c)
                    acc[r][c] += av[r].x * bv[c].x + av[r].y * bv[c].y
                               + av[r].z * bv[c].z + av[r].w * bv[c].w;
        }
        __syncthreads();
    }

    // epilogue: C = max(2 - 2*dot, 0); W = exp(-C/eps) as bf16
    #pragma unroll
    for (int r = 0; r < 8; ++r) {
        int gi = b * NN + i0 + ty + 16 * r;
        #pragma unroll
        for (int c = 0; c < 8; ++c) {
            int gj = j0 + tx + 16 * c;
            float cost = fmaxf(2.0f - 2.0f * acc[r][c], 0.0f);
            float wv = expf(-20.0f * cost);
            __hip_bfloat16 h = __float2bfloat16(wv);
            W[(size_t)gi * MM + gj] = *reinterpret_cast<unsigned short*>(&h);
        }
    }
}

// ---------------- kernel 3: persistent per-batch Sinkhorn (scaled domain) ----------------
__global__ __launch_bounds__(1024) void sinkhorn_kernel(const unsigned short* __restrict__ W,
                                                        float* __restrict__ eu_g,
                                                        float* __restrict__ ev_g) {
    int b = blockIdx.x;
    const unsigned short* Wb = W + (size_t)b * NN * MM;

    __shared__ float eu[NN];
    __shared__ float ev_pad[16 * 36];     // ev[j] at [(j>>5)*36 + (j&31)]
    __shared__ float part[16 * 512];      // per-wave column partials

    int t = threadIdx.x;
    int w = t >> 6, lane = t & 63;
    int sub = lane >> 4, l16 = lane & 15;

    if (t < 16 * 36) ev_pad[t] = 1.0f;    // log_v = 0  ->  ev = 1
    __syncthreads();

    for (int it = 0; it < ITERS; ++it) {
        // ---- phase A: S_i = sum_j W_ij * ev_j ; eu_i = a / S_i ----
        float4 evv[8];
        #pragma unroll
        for (int c = 0; c < 8; ++c) evv[c] = *(const float4*)&ev_pad[l16 * 36 + c * 4];

        #pragma unroll 2
        for (int g = 0; g < 8; ++g) {
            int row = w * 32 + g * 4 + sub;
            const unsigned short* wrow = Wb + (size_t)row * MM + l16 * 32;
            float acc = 0.0f;
            #pragma unroll
            for (int m = 0; m < 4; ++m) {
                uint4 u = ((const uint4*)wrow)[m];
                float4 e0 = evv[2 * m], e1 = evv[2 * m + 1];
                acc += bflo(u.x) * e0.x + bfhi(u.x) * e0.y + bflo(u.y) * e0.z + bfhi(u.y) * e0.w;
                acc += bflo(u.z) * e1.x + bfhi(u.z) * e1.y + bflo(u.w) * e1.z + bfhi(u.w) * e1.w;
            }
            acc += __shfl_xor(acc, 1, 64);
            acc += __shfl_xor(acc, 2, 64);
            acc += __shfl_xor(acc, 4, 64);
            acc += __shfl_xor(acc, 8, 64);
            if (l16 == 0) eu[row] = A_CONST / acc;
        }
        __syncthreads();

        // ---- phase B: T_j = sum_i W_ij * eu_i ; ev_j = b / T_j ----
        float a0 = 0, a1 = 0, a2 = 0, a3 = 0, a4 = 0, a5 = 0, a6 = 0, a7 = 0;
        int ib = w * 32;
        #pragma unroll 4
        for (int ii = 0; ii < 32; ++ii) {
            int i = ib + ii;
            float ui = eu[i];
            uint4 u = *(const uint4*)(Wb + (size_t)i * MM + lane * 8);
            a0 += bflo(u.x) * ui; a1 += bfhi(u.x) * ui;
            a2 += bflo(u.y) * ui; a3 += bfhi(u.y) * ui;
            a4 += bflo(u.z) * ui; a5 += bfhi(u.z) * ui;
            a6 += bflo(u.w) * ui; a7 += bfhi(u.w) * ui;
        }
        float4 p0 = {a0, a1, a2, a3}, p1 = {a4, a5, a6, a7};
        *(float4*)&part[w * 512 + lane * 8]     = p0;
        *(float4*)&part[w * 512 + lane * 8 + 4] = p1;
        __syncthreads();

        if (t < 512) {
            float s = 0.0f;
            #pragma unroll
            for (int ww = 0; ww < 16; ++ww) s += part[ww * 512 + t];
            ev_pad[(t >> 5) * 36 + (t & 31)] = B_CONST / s;
        }
        __syncthreads();
    }

    if (t < NN) {
        eu_g[b * NN + t] = eu[t];
        ev_g[b * MM + t] = ev_pad[(t >> 5) * 36 + (t & 31)];
    }
}

// ---------------- kernel 4: distance_b = sum_ij eu_i W_ij ev_j * (-eps*log W_ij) ----------------
__global__ __launch_bounds__(256) void dist_kernel(const unsigned short* __restrict__ W,
                                                   const float* __restrict__ eu_g,
                                                   const float* __restrict__ ev_g,
                                                   float* __restrict__ dist) {
    int b = blockIdx.x;
    __shared__ float eu[NN], ev[MM];
    __shared__ float red[4];
    int t = threadIdx.x;
    for (int i = t; i < NN; i += 256) eu[i] = eu_g[b * NN + i];
    for (int j = t; j < MM; j += 256) ev[j] = ev_g[b * MM + j];
    __syncthreads();

    const unsigned short* Wb = W + (size_t)b * NN * MM;
    float acc = 0.0f;
    #pragma unroll 2
    for (int s = 0; s < 128; ++s) {
        int flat = s * 256 + t;
        int i = flat >> 6, jg = flat & 63;
        uint4 u = ((const uint4*)(Wb + (size_t)i * MM))[jg];
        float4 e0 = *(const float4*)&ev[jg * 8];
        float4 e1 = *(const float4*)&ev[jg * 8 + 4];
        float w0 = bflo(u.x), w1 = bfhi(u.x), w2 = bflo(u.y), w3 = bfhi(u.y);
        float w4 = bflo(u.z), w5 = bfhi(u.z), w6 = bflo(u.w), w7 = bfhi(u.w);
        float ssum = w0 * __logf(w0) * e0.x + w1 * __logf(w1) * e0.y
                   + w2 * __logf(w2) * e0.z + w3 * __logf(w3) * e0.w
                   + w4 * __logf(w4) * e1.x + w5 * __logf(w5) * e1.y
                   + w6 * __logf(w6) * e1.z + w7 * __logf(w7) * e1.w;
        acc += eu[i] * ssum;
    }
    #pragma unroll
    for (int off = 32; off; off >>= 1) acc += __shfl_xor(acc, off, 64);
    if ((t & 63) == 0) red[t >> 6] = acc;
    __syncthreads();
    if (t == 0) dist[b] = -SINK_EPS_F * (red[0] + red[1] + red[2] + red[3]);
}

// ---------------- kernel 5: mean over batches ----------------
__global__ void mean_kernel(const float* __restrict__ dist, float* __restrict__ out) {
    int lane = threadIdx.x;
    float v = dist[lane];
    #pragma unroll
    for (int off = 32; off; off >>= 1) v += __shfl_xor(v, off, 64);
    if (lane == 0) out[0] = v * (1.0f / 64.0f);
}

extern "C" void kernel_launch(void* const* d_in, const int* in_sizes, int n_in,
                              void* d_out, int out_size, void* d_ws, size_t ws_size,
                              hipStream_t stream) {
    const float* src = (const float*)d_in[0];
    const float* tgt = (const float*)d_in[1];
    char* ws = (char*)d_ws;

    float*          inv_ns = (float*)(ws);
    float*          inv_nt = (float*)(ws + 131072);
    unsigned short* W      = (unsigned short*)(ws + 262144);
    float*          eu_g   = (float*)(ws + 262144 + 33554432);
    float*          ev_g   = (float*)(ws + 262144 + 33554432 + 131072);
    float*          dist   = (float*)(ws + 262144 + 33554432 + 262144);
    float*          out    = (float*)d_out;

    hipLaunchKernelGGL(norm_kernel,     dim3(16384), dim3(256),  0, stream, src, tgt, inv_ns, inv_nt);
    hipLaunchKernelGGL(cost_kernel,     dim3(1024),  dim3(256),  0, stream, src, tgt, inv_ns, inv_nt, W);
    hipLaunchKernelGGL(sinkhorn_kernel, dim3(64),    dim3(1024), 0, stream, W, eu_g, ev_g);
    hipLaunchKernelGGL(dist_kernel,     dim3(64),    dim3(256),  0, stream, W, eu_g, ev_g, dist);
    hipLaunchKernelGGL(mean_kernel,     dim3(1),     dim3(64),   0, stream, dist, out);
}